// Round 4
// baseline (336.102 us; speedup 1.0000x reference)
//
#include <hip/hip_runtime.h>
#include <stdint.h>

// Problem constants (fixed by setup_inputs)
#define DD   128      // feature dim D
#define TT   64       // time steps
#define BB   8192     // batch
#define NPOW 8        // Taylor degree for expm: ||tW||<=~1.3 -> remainder 1.3^9/9! ~ 3e-5

typedef float  f32x4  __attribute__((ext_vector_type(4)));
typedef __bf16 bf16x8 __attribute__((ext_vector_type(8)));

// RTN-even float -> bf16 bits
__device__ __forceinline__ unsigned short f2bf(float f) {
  unsigned u = __builtin_bit_cast(unsigned, f);
  u += 0x7fffu + ((u >> 16) & 1u);
  return (unsigned short)(u >> 16);
}

// ---------------------------------------------------------------------------
// x (fp32) -> xb (bf16 bits), 8192x128, 4 elems/thread, fully coalesced
// ---------------------------------------------------------------------------
__global__ void cvt_x_kernel(const float* __restrict__ x, unsigned short* __restrict__ xb) {
  int i = (blockIdx.x * 256 + threadIdx.x) * 4;
  float4 v = *(const float4*)(x + i);
  unsigned long long u =  (unsigned long long)f2bf(v.x)
                       | ((unsigned long long)f2bf(v.y) << 16)
                       | ((unsigned long long)f2bf(v.z) << 32)
                       | ((unsigned long long)f2bf(v.w) << 48);
  *(unsigned long long*)(xb + i) = u;
}

// ---------------------------------------------------------------------------
// Wt = W^T (128x128 fp32). grid 16 blocks of 32x32 tiles, 256 threads.
// Wt goes to Wp slot 0. Ladder runs on W^T so (W^T)^n = (W^n)^T and combine
// reads/writes stay coalesced.
// ---------------------------------------------------------------------------
__global__ void transpose_kernel(const float* __restrict__ W, float* __restrict__ Wt) {
  __shared__ float t[32][33];
  int bx = blockIdx.x & 3, by = blockIdx.x >> 2;
  int r = threadIdx.x >> 3;          // 0..31
  int c = (threadIdx.x & 7) * 4;     // 4 cols/thread
  float4 v = *(const float4*)(W + (by * 32 + r) * DD + bx * 32 + c);
  t[r][c] = v.x; t[r][c + 1] = v.y; t[r][c + 2] = v.z; t[r][c + 3] = v.w;
  __syncthreads();
  float4 o = { t[c + 0][r], t[c + 1][r], t[c + 2][r], t[c + 3][r] };
  *(float4*)(Wt + (bx * 32 + r) * DD + by * 32 + c) = o;
}

// ---------------------------------------------------------------------------
// fp32 power ladder on W^T. Wp slot (n-1) holds (W^T)^n.
// grid = nmat*16 blocks (16 row-blocks of 8 rows), 256 threads, float4 I/O.
// ---------------------------------------------------------------------------
__global__ __launch_bounds__(256) void powmm_kernel(float* __restrict__ Wp,
                                                    int aPow, int bBase, int dstBase) {
  int mat = blockIdx.x >> 4;
  int rb  = blockIdx.x & 15;
  const float* A = Wp + (aPow - 1) * DD * DD;
  const float* B = Wp + (bBase + mat - 1) * DD * DD;
  float* C = Wp + (dstBase + mat - 1) * DD * DD;

  __shared__ float Bs[DD * DD];      // 64 KB
  __shared__ float As[8 * DD];       // 4 KB
  for (int i = threadIdx.x; i < DD * DD / 4; i += 256)
    ((float4*)Bs)[i] = ((const float4*)B)[i];
  for (int i = threadIdx.x; i < 8 * DD / 4; i += 256)
    ((float4*)As)[i] = ((const float4*)(A + rb * 8 * DD))[i];
  __syncthreads();

  int r  = threadIdx.x >> 5;         // 0..7 local row
  int c0 = (threadIdx.x & 31) * 4;   // 4 cols/thread
  f32x4 acc = {0.f, 0.f, 0.f, 0.f};
  for (int k = 0; k < DD; ++k) {
    float a = As[r * DD + k];
    f32x4 b = *(const f32x4*)(Bs + k * DD + c0);
    acc += a * b;
  }
  *(f32x4*)(C + (rb * 8 + r) * DD + c0) = acc;
}

// ---------------------------------------------------------------------------
// Combine: P_j^T = I + sum_{n=1..8} (t^n/n!) (W^T)^n,  t = j*0.01, bf16 out.
// Fully coalesced float4 reads + 8B writes. grid = 64*16 blocks, 256 threads.
// ---------------------------------------------------------------------------
__global__ __launch_bounds__(256) void combine_kernel(const float* __restrict__ Wp,
                                                      unsigned short* __restrict__ Pb) {
  int j    = blockIdx.x >> 4;
  int part = blockIdx.x & 15;
  float c[NPOW];
  double t = (double)j * 0.01, cc = 1.0;
  for (int n = 1; n <= NPOW; ++n) { cc *= t / (double)n; c[n - 1] = (float)cc; }

  int e0 = part * 1024 + threadIdx.x * 4;   // element offset within 128x128
  f32x4 acc;
#pragma unroll
  for (int i = 0; i < 4; ++i) {
    int e = e0 + i;
    acc[i] = ((e >> 7) == (e & 127)) ? 1.0f : 0.0f;   // identity
  }
#pragma unroll
  for (int n = 0; n < NPOW; ++n) {
    f32x4 w = *(const f32x4*)(Wp + n * DD * DD + e0);
    acc += c[n] * w;
  }
  unsigned long long u =  (unsigned long long)f2bf(acc[0])
                       | ((unsigned long long)f2bf(acc[1]) << 16)
                       | ((unsigned long long)f2bf(acc[2]) << 32)
                       | ((unsigned long long)f2bf(acc[3]) << 48);
  *(unsigned long long*)(Pb + j * DD * DD + e0) = u;
}

// ---------------------------------------------------------------------------
// Main GEMM: out[b, j*128+d] = sum_k xb[b,k] * P_j[k,d]
// Operands direct from L2 (xb 2MiB + Pb 2MiB resident); no LDS at all.
//
// SWAPPED-OPERAND MFMA epilogue: acc = mfma(bf, af) computes D^T = P^T * x^T,
// so col(lane&15) = batch row m, row(quad*4+r) = feature d. Each lane holds 4
// CONSECUTIVE d for one output row -> direct aligned float4 nontemporal store.
// This replaces the old LDS-transpose epilogue (64 scalar ds_writes + 2
// barriers + 16 ds_read_b128 per thread) with just 16 stores, and LDS=0
// lifts the occupancy cap from 4 to ~8 blocks/CU.
//
// Grid: 1-D 4096, j-FAST dispatch with XCD-stable swizzle:
//   bt = n>>6, jo = n&63, j = (jo&7)*8 + (jo>>3)
// XCD = n%8 = jo%8 stable across bt: XCD k owns j in [8k,8k+8), keeping its
// 8 P-matrices (256 KiB) + xb L2-resident; concurrent bt-group writes one
// contiguous 4-MiB output slab.
// ---------------------------------------------------------------------------
__global__ __launch_bounds__(256, 4) void gemm_kernel(
    const unsigned short* __restrict__ xb,   // 8192 x 128 bf16 row-major
    const unsigned short* __restrict__ Pb,   // 64 x (128 d x 128 k) bf16 (P^T per j)
    float* __restrict__ out) {               // 8192 x (64*128) fp32
  const int n    = blockIdx.x;
  const int bt   = n >> 6;
  const int jo   = n & 63;
  const int j    = ((jo & 7) << 3) | (jo >> 3);   // XCD-stable bijection
  const int tid  = threadIdx.x;
  const int w    = tid >> 6;       // wave 0..3
  const int l    = tid & 63;
  const int quad = l >> 4;         // 0..3
  const int li   = l & 15;

  const int mq = (w >> 1) * 64;    // wave's 64x64 quadrant
  const int nq = (w & 1) * 64;

  const unsigned short* gA = xb + bt * DD * DD;
  const unsigned short* gB = Pb + j * DD * DD;

  f32x4 acc[4][4];
#pragma unroll
  for (int mt = 0; mt < 4; ++mt)
#pragma unroll
    for (int nt = 0; nt < 4; ++nt) acc[mt][nt] = (f32x4){0.f, 0.f, 0.f, 0.f};

#pragma unroll
  for (int ks = 0; ks < 4; ++ks) {
    bf16x8 af[4], bf[4];
#pragma unroll
    for (int mt = 0; mt < 4; ++mt)
      af[mt] = *(const bf16x8*)(gA + (mq + mt * 16 + li) * DD + ks * 32 + quad * 8);
#pragma unroll
    for (int nt = 0; nt < 4; ++nt)
      bf[nt] = *(const bf16x8*)(gB + (nq + nt * 16 + li) * DD + ks * 32 + quad * 8);
    // Swapped operands: bf as A-fragment (rows = d), af as B-fragment
    // (cols = m). Same loaded fragments, transposed result in registers.
#pragma unroll
    for (int mt = 0; mt < 4; ++mt)
#pragma unroll
      for (int nt = 0; nt < 4; ++nt)
        acc[mt][nt] = __builtin_amdgcn_mfma_f32_16x16x32_bf16(bf[nt], af[mt], acc[mt][nt], 0, 0, 0);
  }

  // ---- Epilogue: direct float4 stores ----
  // D^T layout: m = mq + mt*16 + (lane&15), d = nq + nt*16 + quad*4 + r.
  // acc[mt][nt] = 4 consecutive d for row m -> one 16B-aligned float4 store.
  // Per wave-instr: 16 rows x 64B (4 quads complete each 64B span; the 4 nt
  // stores complete each 128B line back-to-back -> L2 write-combines).
  const size_t orow = (size_t)(TT * DD);
  float* obase = out + (size_t)(bt * DD) * orow + j * DD;
#pragma unroll
  for (int mt = 0; mt < 4; ++mt) {
    float* orow_p = obase + (size_t)(mq + mt * 16 + li) * orow + quad * 4;
#pragma unroll
    for (int nt = 0; nt < 4; ++nt)
      __builtin_nontemporal_store(acc[mt][nt], (f32x4*)(orow_p + nq + nt * 16));
  }
}

// ---------------------------------------------------------------------------
extern "C" void kernel_launch(void* const* d_in, const int* in_sizes, int n_in,
                              void* d_out, int out_size, void* d_ws, size_t ws_size,
                              hipStream_t stream) {
  const float* x = (const float*)d_in[0];
  const float* W = (const float*)d_in[1];
  float* out = (float*)d_out;

  // Workspace: Wp = 8 fp32 128x128 slots ((W^T)^1..(W^T)^8) = 512 KB,
  //            Pb = 64 * 128*128 bf16 = 2 MiB,  xb = 8192*128 bf16 = 2 MiB
  float* Wp = (float*)d_ws;
  unsigned short* Pb = (unsigned short*)((char*)d_ws + NPOW * DD * DD * sizeof(float));
  unsigned short* xb = Pb + TT * DD * DD;

  cvt_x_kernel<<<BB * DD / (256 * 4), 256, 0, stream>>>(x, xb);
  transpose_kernel<<<16, 256, 0, stream>>>(W, Wp);          // slot 0 = W^T

  // log-depth ladder on W^T: n=2 | n=3,4 | n=5..8
  powmm_kernel<<<16, 256, 0, stream>>>(Wp, 1, 1, 2);
  powmm_kernel<<<32, 256, 0, stream>>>(Wp, 2, 1, 3);
  powmm_kernel<<<64, 256, 0, stream>>>(Wp, 4, 1, 5);

  combine_kernel<<<TT * 16, 256, 0, stream>>>(Wp, Pb);

  gemm_kernel<<<4096, 256, 0, stream>>>(xb, Pb, out);
}

// Round 5
// 327.393 us; speedup vs baseline: 1.0266x; 1.0266x over previous
//
#include <hip/hip_runtime.h>
#include <stdint.h>

// Problem constants (fixed by setup_inputs)
#define DD   128      // feature dim D
#define TT   64       // time steps
#define BB   8192     // batch
#define NPOW 8        // Taylor degree for expm: ||tW||<=~1.3 -> remainder 1.3^9/9! ~ 3e-5

typedef float  f32x4  __attribute__((ext_vector_type(4)));
typedef __bf16 bf16x8 __attribute__((ext_vector_type(8)));

// RTN-even float -> bf16 bits
__device__ __forceinline__ unsigned short f2bf(float f) {
  unsigned u = __builtin_bit_cast(unsigned, f);
  u += 0x7fffu + ((u >> 16) & 1u);
  return (unsigned short)(u >> 16);
}

// ---------------------------------------------------------------------------
// x (fp32) -> xb (bf16 bits), 8192x128, 4 elems/thread, fully coalesced
// ---------------------------------------------------------------------------
__global__ void cvt_x_kernel(const float* __restrict__ x, unsigned short* __restrict__ xb) {
  int i = (blockIdx.x * 256 + threadIdx.x) * 4;
  float4 v = *(const float4*)(x + i);
  unsigned long long u =  (unsigned long long)f2bf(v.x)
                       | ((unsigned long long)f2bf(v.y) << 16)
                       | ((unsigned long long)f2bf(v.z) << 32)
                       | ((unsigned long long)f2bf(v.w) << 48);
  *(unsigned long long*)(xb + i) = u;
}

// ---------------------------------------------------------------------------
// Wt = W^T (128x128 fp32). grid 16 blocks of 32x32 tiles, 256 threads.
// Wt goes to Wp slot 0. Ladder runs on W^T so (W^T)^n = (W^n)^T and combine
// reads/writes stay coalesced.
// ---------------------------------------------------------------------------
__global__ void transpose_kernel(const float* __restrict__ W, float* __restrict__ Wt) {
  __shared__ float t[32][33];
  int bx = blockIdx.x & 3, by = blockIdx.x >> 2;
  int r = threadIdx.x >> 3;          // 0..31
  int c = (threadIdx.x & 7) * 4;     // 4 cols/thread
  float4 v = *(const float4*)(W + (by * 32 + r) * DD + bx * 32 + c);
  t[r][c] = v.x; t[r][c + 1] = v.y; t[r][c + 2] = v.z; t[r][c + 3] = v.w;
  __syncthreads();
  float4 o = { t[c + 0][r], t[c + 1][r], t[c + 2][r], t[c + 3][r] };
  *(float4*)(Wt + (bx * 32 + r) * DD + by * 32 + c) = o;
}

// ---------------------------------------------------------------------------
// fp32 power ladder on W^T. Wp slot (n-1) holds (W^T)^n.
// grid = nmat*16 blocks (16 row-blocks of 8 rows), 256 threads, float4 I/O.
// ---------------------------------------------------------------------------
__global__ __launch_bounds__(256) void powmm_kernel(float* __restrict__ Wp,
                                                    int aPow, int bBase, int dstBase) {
  int mat = blockIdx.x >> 4;
  int rb  = blockIdx.x & 15;
  const float* A = Wp + (aPow - 1) * DD * DD;
  const float* B = Wp + (bBase + mat - 1) * DD * DD;
  float* C = Wp + (dstBase + mat - 1) * DD * DD;

  __shared__ float Bs[DD * DD];      // 64 KB
  __shared__ float As[8 * DD];       // 4 KB
  for (int i = threadIdx.x; i < DD * DD / 4; i += 256)
    ((float4*)Bs)[i] = ((const float4*)B)[i];
  for (int i = threadIdx.x; i < 8 * DD / 4; i += 256)
    ((float4*)As)[i] = ((const float4*)(A + rb * 8 * DD))[i];
  __syncthreads();

  int r  = threadIdx.x >> 5;         // 0..7 local row
  int c0 = (threadIdx.x & 31) * 4;   // 4 cols/thread
  f32x4 acc = {0.f, 0.f, 0.f, 0.f};
  for (int k = 0; k < DD; ++k) {
    float a = As[r * DD + k];
    f32x4 b = *(const f32x4*)(Bs + k * DD + c0);
    acc += a * b;
  }
  *(f32x4*)(C + (rb * 8 + r) * DD + c0) = acc;
}

// ---------------------------------------------------------------------------
// Combine: P_j^T = I + sum_{n=1..8} (t^n/n!) (W^T)^n,  t = j*0.01, bf16 out.
// Fully coalesced float4 reads + 8B writes. grid = 64*16 blocks, 256 threads.
// ---------------------------------------------------------------------------
__global__ __launch_bounds__(256) void combine_kernel(const float* __restrict__ Wp,
                                                      unsigned short* __restrict__ Pb) {
  int j    = blockIdx.x >> 4;
  int part = blockIdx.x & 15;
  float c[NPOW];
  double t = (double)j * 0.01, cc = 1.0;
  for (int n = 1; n <= NPOW; ++n) { cc *= t / (double)n; c[n - 1] = (float)cc; }

  int e0 = part * 1024 + threadIdx.x * 4;   // element offset within 128x128
  f32x4 acc;
#pragma unroll
  for (int i = 0; i < 4; ++i) {
    int e = e0 + i;
    acc[i] = ((e >> 7) == (e & 127)) ? 1.0f : 0.0f;   // identity
  }
#pragma unroll
  for (int n = 0; n < NPOW; ++n) {
    f32x4 w = *(const f32x4*)(Wp + n * DD * DD + e0);
    acc += c[n] * w;
  }
  unsigned long long u =  (unsigned long long)f2bf(acc[0])
                       | ((unsigned long long)f2bf(acc[1]) << 16)
                       | ((unsigned long long)f2bf(acc[2]) << 32)
                       | ((unsigned long long)f2bf(acc[3]) << 48);
  *(unsigned long long*)(Pb + j * DD * DD + e0) = u;
}

// ---------------------------------------------------------------------------
// Main GEMM: out[b, j*128+d] = sum_k xb[b,k] * P_j[k,d]
// Operands direct from L2 (xb 2MiB + Pb 2MiB resident); no LDS at all.
//
// SWAPPED-OPERAND MFMA epilogue: acc = mfma(bf, af) computes D^T = P^T * x^T,
// so col(lane&15) = batch row m, row(quad*4+r) = feature d. Each lane holds 4
// CONSECUTIVE d for one output row -> direct aligned float4 store.
//
// R5 ablation: PLAIN stores (no nontemporal). The harness fill kernel proves
// plain streaming stores hit 6.4 TB/s on this chip; nt (no-allocate) was the
// one un-ablated constant on the store path across all prior rounds and is
// suspected of forcing partial-line DRAM writes (16 scattered 64B segments
// per store instr with no L2 aggregation).
//
// Grid: 1-D 4096, j-FAST dispatch with XCD-stable swizzle:
//   bt = n>>6, jo = n&63, j = (jo&7)*8 + (jo>>3)
// XCD = n%8 = jo%8 stable across bt: XCD k owns j in [8k,8k+8), keeping its
// 8 P-matrices (256 KiB) + xb L2-resident; concurrent bt-group writes one
// contiguous 4-MiB output slab.
// ---------------------------------------------------------------------------
__global__ __launch_bounds__(256, 4) void gemm_kernel(
    const unsigned short* __restrict__ xb,   // 8192 x 128 bf16 row-major
    const unsigned short* __restrict__ Pb,   // 64 x (128 d x 128 k) bf16 (P^T per j)
    float* __restrict__ out) {               // 8192 x (64*128) fp32
  const int n    = blockIdx.x;
  const int bt   = n >> 6;
  const int jo   = n & 63;
  const int j    = ((jo & 7) << 3) | (jo >> 3);   // XCD-stable bijection
  const int tid  = threadIdx.x;
  const int w    = tid >> 6;       // wave 0..3
  const int l    = tid & 63;
  const int quad = l >> 4;         // 0..3
  const int li   = l & 15;

  const int mq = (w >> 1) * 64;    // wave's 64x64 quadrant
  const int nq = (w & 1) * 64;

  const unsigned short* gA = xb + bt * DD * DD;
  const unsigned short* gB = Pb + j * DD * DD;

  f32x4 acc[4][4];
#pragma unroll
  for (int mt = 0; mt < 4; ++mt)
#pragma unroll
    for (int nt = 0; nt < 4; ++nt) acc[mt][nt] = (f32x4){0.f, 0.f, 0.f, 0.f};

#pragma unroll
  for (int ks = 0; ks < 4; ++ks) {
    bf16x8 af[4], bf[4];
#pragma unroll
    for (int mt = 0; mt < 4; ++mt)
      af[mt] = *(const bf16x8*)(gA + (mq + mt * 16 + li) * DD + ks * 32 + quad * 8);
#pragma unroll
    for (int nt = 0; nt < 4; ++nt)
      bf[nt] = *(const bf16x8*)(gB + (nq + nt * 16 + li) * DD + ks * 32 + quad * 8);
    // Swapped operands: bf as A-fragment (rows = d), af as B-fragment
    // (cols = m). Same loaded fragments, transposed result in registers.
#pragma unroll
    for (int mt = 0; mt < 4; ++mt)
#pragma unroll
      for (int nt = 0; nt < 4; ++nt)
        acc[mt][nt] = __builtin_amdgcn_mfma_f32_16x16x32_bf16(bf[nt], af[mt], acc[mt][nt], 0, 0, 0);
  }

  // ---- Epilogue: direct float4 stores (PLAIN — R5 nt ablation) ----
  // D^T layout: m = mq + mt*16 + (lane&15), d = nq + nt*16 + quad*4 + r.
  // acc[mt][nt] = 4 consecutive d for row m -> one 16B-aligned float4 store.
  const size_t orow = (size_t)(TT * DD);
  float* obase = out + (size_t)(bt * DD) * orow + j * DD;
#pragma unroll
  for (int mt = 0; mt < 4; ++mt) {
    float* orow_p = obase + (size_t)(mq + mt * 16 + li) * orow + quad * 4;
#pragma unroll
    for (int nt = 0; nt < 4; ++nt)
      *(f32x4*)(orow_p + nq + nt * 16) = acc[mt][nt];
  }
}

// ---------------------------------------------------------------------------
extern "C" void kernel_launch(void* const* d_in, const int* in_sizes, int n_in,
                              void* d_out, int out_size, void* d_ws, size_t ws_size,
                              hipStream_t stream) {
  const float* x = (const float*)d_in[0];
  const float* W = (const float*)d_in[1];
  float* out = (float*)d_out;

  // Workspace: Wp = 8 fp32 128x128 slots ((W^T)^1..(W^T)^8) = 512 KB,
  //            Pb = 64 * 128*128 bf16 = 2 MiB,  xb = 8192*128 bf16 = 2 MiB
  float* Wp = (float*)d_ws;
  unsigned short* Pb = (unsigned short*)((char*)d_ws + NPOW * DD * DD * sizeof(float));
  unsigned short* xb = Pb + TT * DD * DD;

  cvt_x_kernel<<<BB * DD / (256 * 4), 256, 0, stream>>>(x, xb);
  transpose_kernel<<<16, 256, 0, stream>>>(W, Wp);          // slot 0 = W^T

  // log-depth ladder on W^T: n=2 | n=3,4 | n=5..8
  powmm_kernel<<<16, 256, 0, stream>>>(Wp, 1, 1, 2);
  powmm_kernel<<<32, 256, 0, stream>>>(Wp, 2, 1, 3);
  powmm_kernel<<<64, 256, 0, stream>>>(Wp, 4, 1, 5);

  combine_kernel<<<TT * 16, 256, 0, stream>>>(Wp, Pb);

  gemm_kernel<<<4096, 256, 0, stream>>>(xb, Pb, out);
}